// Round 6
// baseline (546.042 us; speedup 1.0000x reference)
//
#include <hip/hip_runtime.h>
#include <hip/hip_bf16.h>

#define B_ 128
#define T_ 512
#define H_ 128
#define V_ 64
#define G4_ 512  // 4*H

typedef _Float16 h2_t __attribute__((ext_vector_type(2)));
typedef _Float16 h8_t __attribute__((ext_vector_type(8)));
struct h8s { h2_t p[4]; };

__device__ __forceinline__ float dot2f(h2_t a, h2_t b, float c) {
#if __has_builtin(__builtin_amdgcn_fdot2)
  return __builtin_amdgcn_fdot2(a, b, c, false);
#else
  return fmaf((float)a[1], (float)b[1], fmaf((float)a[0], (float)b[0], c));
#endif
}

__device__ __forceinline__ float ex2(float x) {
#if __has_builtin(__builtin_amdgcn_exp2f)
  return __builtin_amdgcn_exp2f(x);
#else
  return exp2f(x);
#endif
}

__device__ __forceinline__ float rcpf_(float x) {
#if __has_builtin(__builtin_amdgcn_rcpf)
  return __builtin_amdgcn_rcpf(x);
#else
  return 1.0f / x;
#endif
}

// DPP quad-perm controls
#define QP_XOR1 0xB1  // [1,0,3,2]
#define QP_XOR2 0x4E  // [2,3,0,1]
#define QP_BC0 0x00
#define QP_BC1 0x55
#define QP_BC2 0xAA
#define QP_BC3 0xFF

template <int CTRL>
__device__ __forceinline__ float qperm(float v) {
#if __has_builtin(__builtin_amdgcn_update_dpp)
  return __builtin_bit_cast(
      float, __builtin_amdgcn_update_dpp(0, __builtin_bit_cast(int, v), CTRL,
                                         0xf, 0xf, true));
#else
  int lane = (int)(threadIdx.x & 3);
  int src;
  if constexpr (CTRL == QP_XOR1) src = lane ^ 1;
  else if constexpr (CTRL == QP_XOR2) src = lane ^ 2;
  else src = CTRL & 3;
  return __shfl(v, ((int)threadIdx.x & ~3) + src, 64);
#endif
}

// ---------------------------------------------------------------------------
// K1: P[dir][v][k*4+g] = dot(emb[v,:], w_ih[dir][g*128+k,:]) + biases
// ---------------------------------------------------------------------------
__global__ __launch_bounds__(512) void k_tables(
    const float* __restrict__ emb,
    const float* __restrict__ w_ih_f, const float* __restrict__ b_ih_f,
    const float* __restrict__ b_hh_f,
    const float* __restrict__ w_ih_b, const float* __restrict__ b_ih_b,
    const float* __restrict__ b_hh_b,
    float* __restrict__ Ptab) {
  const int dir = blockIdx.x >> 6;
  const int v = blockIdx.x & 63;
  const int j = threadIdx.x;  // row = g*128 + k
  const float* w_ih = dir ? w_ih_b : w_ih_f;
  const float* bi = dir ? b_ih_b : b_ih_f;
  const float* bh = dir ? b_hh_b : b_hh_f;
  const float4* e4 = (const float4*)(emb + v * H_);
  const float4* w4 = (const float4*)(w_ih + j * H_);
  float a0 = 0.f, a1 = 0.f, a2 = 0.f, a3 = 0.f;
#pragma unroll
  for (int q = 0; q < H_ / 4; ++q) {
    float4 e = e4[q];
    float4 w = w4[q];
    a0 = fmaf(e.x, w.x, a0);
    a1 = fmaf(e.y, w.y, a1);
    a2 = fmaf(e.z, w.z, a2);
    a3 = fmaf(e.w, w.w, a3);
  }
  const int g = j >> 7, k = j & 127;
  Ptab[dir * (V_ * G4_) + v * G4_ + (k << 2) + g] =
      (a0 + a1) + (a2 + a3) + bi[j] + bh[j];
}

// ---------------------------------------------------------------------------
// K2: TWO same-direction sequences per 512-thread block, interleaved IN-THREAD
// (shared wr weights, doubled dot/nonlin streams -> seq A's serial chains
// hide under seq B's VALU work within the same wave).
// Lane mapping per seq: wave w, lane l -> k = w*16+(l>>2), gate g = l&3.
// grid = 128: dir = bid>>6, batch pair = bid&63 -> batches 2p, 2p+1.
// 512-thr block avoids the gfx950 1024-thr 64-VGPR clamp (rounds 4/5).
// ---------------------------------------------------------------------------
__global__ __launch_bounds__(512, 1) void k_scan(
    const int* __restrict__ x,
    const float* __restrict__ w_hh_f,
    const float* __restrict__ w_hh_b,
    const float* __restrict__ Ptab,
    _Float16* __restrict__ hs) {
  __shared__ __align__(16) float P[V_ * G4_];          // 128 KB (shared, per dir)
  __shared__ int xoff[2][T_];                          // 4 KB
  __shared__ __align__(16) _Float16 hb[2][2][H_];      // 1 KB  [seq][buf][k]
  __shared__ __align__(16) _Float16 hist[2][16][H_];   // 8 KB  (16-step flush)

  const int tid = threadIdx.x;
  const int dir = blockIdx.x >> 6;
  const int pr = blockIdx.x & 63;
  const int b0 = pr << 1;
  const int l = tid & 63;
  const int w = tid >> 6;
  const int g = l & 3;
  const int k = (w << 4) + (l >> 2);
  const int k4g = (k << 2) + g;

  // stage P table, coalesced float4
  {
    const float4* src = (const float4*)(Ptab + dir * (V_ * G4_));
    float4* dst = (float4*)P;
#pragma unroll
    for (int i = 0; i < (V_ * G4_ / 4) / 512; ++i)
      dst[tid + i * 512] = src[tid + i * 512];
  }
  xoff[0][tid] = x[(b0 << 9) + tid] << 9;
  xoff[1][tid] = x[((b0 + 1) << 9) + tid] << 9;
  if (tid < H_) {
    hb[0][0][tid] = (_Float16)0.f;
    hb[1][0][tid] = (_Float16)0.f;
  }

  // weight quarters: rows j*128+k, elements [g*32, g*32+32), fp16 pairs
  // SHARED by both sequences (the whole point of pairing).
  const float* W = dir ? w_hh_b : w_hh_f;
  h2_t wr[4][16];
#pragma unroll
  for (int j = 0; j < 4; ++j) {
    const float2* wp = (const float2*)(W + (j * H_ + k) * H_ + g * 32);
#pragma unroll
    for (int e = 0; e < 16; ++e) {
      float2 ww = wp[e];
      wr[j][e] = h2_t{(_Float16)ww.x, (_Float16)ww.y};
    }
  }

  // per-lane nonlinearity constants: sigm for g in {0,1,3}, tanh for g==2
  const float nm = (g == 2) ? -2.8853900817779268f : -1.4426950408889634f;
  const float sa = (g == 2) ? 2.f : 1.f;
  const float sb = (g == 2) ? -1.f : 0.f;

  float cA = 0.f, cB = 0.f;  // c[k], replicated across the quad

  __syncthreads();

  const int t0 = dir ? (T_ - 1) : 0;
  float pvA = P[xoff[0][t0] + k4g];
  float pvB = P[xoff[1][t0] + k4g];

  int cur = 0;
  for (int s = 0; s < T_; ++s) {
    const int t = dir ? (T_ - 1 - s) : s;
    // h quarter g for both seqs: 8x ds_read_b128 (16-lane broadcast each)
    const h8_t* hqA = (const h8_t*)(&hb[0][cur][g << 5]);
    const h8_t* hqB = (const h8_t*)(&hb[1][cur][g << 5]);
    h8s qA0 = __builtin_bit_cast(h8s, hqA[0]);
    h8s qA1 = __builtin_bit_cast(h8s, hqA[1]);
    h8s qA2 = __builtin_bit_cast(h8s, hqA[2]);
    h8s qA3 = __builtin_bit_cast(h8s, hqA[3]);
    h8s qB0 = __builtin_bit_cast(h8s, hqB[0]);
    h8s qB1 = __builtin_bit_cast(h8s, hqB[1]);
    h8s qB2 = __builtin_bit_cast(h8s, hqB[2]);
    h8s qB3 = __builtin_bit_cast(h8s, hqB[3]);

    // prefetch next step's P values
    const int sn = (s < T_ - 1) ? s + 1 : s;
    const int tn = dir ? (T_ - 1 - sn) : sn;
    const float pvnA = P[xoff[0][tn] + k4g];
    const float pvnB = P[xoff[1][tn] + k4g];

    float aA0 = 0.f, aA1 = 0.f, aA2 = 0.f, aA3 = 0.f;
    float aB0 = 0.f, aB1 = 0.f, aB2 = 0.f, aB3 = 0.f;
#pragma unroll
    for (int e = 0; e < 4; ++e) {
      aA0 = dot2f(qA0.p[e], wr[0][e], aA0);
      aA1 = dot2f(qA0.p[e], wr[1][e], aA1);
      aA2 = dot2f(qA0.p[e], wr[2][e], aA2);
      aA3 = dot2f(qA0.p[e], wr[3][e], aA3);
      aB0 = dot2f(qB0.p[e], wr[0][e], aB0);
      aB1 = dot2f(qB0.p[e], wr[1][e], aB1);
      aB2 = dot2f(qB0.p[e], wr[2][e], aB2);
      aB3 = dot2f(qB0.p[e], wr[3][e], aB3);
    }
#pragma unroll
    for (int e = 0; e < 4; ++e) {
      aA0 = dot2f(qA1.p[e], wr[0][4 + e], aA0);
      aA1 = dot2f(qA1.p[e], wr[1][4 + e], aA1);
      aA2 = dot2f(qA1.p[e], wr[2][4 + e], aA2);
      aA3 = dot2f(qA1.p[e], wr[3][4 + e], aA3);
      aB0 = dot2f(qB1.p[e], wr[0][4 + e], aB0);
      aB1 = dot2f(qB1.p[e], wr[1][4 + e], aB1);
      aB2 = dot2f(qB1.p[e], wr[2][4 + e], aB2);
      aB3 = dot2f(qB1.p[e], wr[3][4 + e], aB3);
    }
#pragma unroll
    for (int e = 0; e < 4; ++e) {
      aA0 = dot2f(qA2.p[e], wr[0][8 + e], aA0);
      aA1 = dot2f(qA2.p[e], wr[1][8 + e], aA1);
      aA2 = dot2f(qA2.p[e], wr[2][8 + e], aA2);
      aA3 = dot2f(qA2.p[e], wr[3][8 + e], aA3);
      aB0 = dot2f(qB2.p[e], wr[0][8 + e], aB0);
      aB1 = dot2f(qB2.p[e], wr[1][8 + e], aB1);
      aB2 = dot2f(qB2.p[e], wr[2][8 + e], aB2);
      aB3 = dot2f(qB2.p[e], wr[3][8 + e], aB3);
    }
#pragma unroll
    for (int e = 0; e < 4; ++e) {
      aA0 = dot2f(qA3.p[e], wr[0][12 + e], aA0);
      aA1 = dot2f(qA3.p[e], wr[1][12 + e], aA1);
      aA2 = dot2f(qA3.p[e], wr[2][12 + e], aA2);
      aA3 = dot2f(qA3.p[e], wr[3][12 + e], aA3);
      aB0 = dot2f(qB3.p[e], wr[0][12 + e], aB0);
      aB1 = dot2f(qB3.p[e], wr[1][12 + e], aB1);
      aB2 = dot2f(qB3.p[e], wr[2][12 + e], aB2);
      aB3 = dot2f(qB3.p[e], wr[3][12 + e], aB3);
    }

    // quad transpose-reduce both seqs
    float sA0 = aA0 + qperm<QP_XOR1>(aA0);
    float sA1 = aA1 + qperm<QP_XOR1>(aA1);
    float sA2 = aA2 + qperm<QP_XOR1>(aA2);
    float sA3 = aA3 + qperm<QP_XOR1>(aA3);
    float sB0 = aB0 + qperm<QP_XOR1>(aB0);
    float sB1 = aB1 + qperm<QP_XOR1>(aB1);
    float sB2 = aB2 + qperm<QP_XOR1>(aB2);
    float sB3 = aB3 + qperm<QP_XOR1>(aB3);
    float AA = (g & 1) ? sA1 : sA0;
    float BA = (g & 1) ? sA3 : sA2;
    float AB = (g & 1) ? sB1 : sB0;
    float BB = (g & 1) ? sB3 : sB2;
    float A2A = AA + qperm<QP_XOR2>(AA);
    float B2A = BA + qperm<QP_XOR2>(BA);
    float A2B = AB + qperm<QP_XOR2>(AB);
    float B2B = BB + qperm<QP_XOR2>(BB);
    float gvA = ((g & 2) ? B2A : A2A) + pvA;
    float gvB = ((g & 2) ? B2B : A2B) + pvB;

    // nonlinearity (uniform code, per-lane constants)
    float yA = fmaf(sa, rcpf_(1.f + ex2(nm * gvA)), sb);
    float yB = fmaf(sa, rcpf_(1.f + ex2(nm * gvB)), sb);

    // broadcast all 4 gates within the quad
    float yiA = qperm<QP_BC0>(yA);
    float yfA = qperm<QP_BC1>(yA);
    float ygA = qperm<QP_BC2>(yA);
    float yoA = qperm<QP_BC3>(yA);
    float yiB = qperm<QP_BC0>(yB);
    float yfB = qperm<QP_BC1>(yB);
    float ygB = qperm<QP_BC2>(yB);
    float yoB = qperm<QP_BC3>(yB);

    cA = fmaf(yfA, cA, yiA * ygA);
    cB = fmaf(yfB, cB, yiB * ygB);
    float tcA = fmaf(2.f, rcpf_(1.f + ex2(-2.8853900817779268f * cA)), -1.f);
    float tcB = fmaf(2.f, rcpf_(1.f + ex2(-2.8853900817779268f * cB)), -1.f);
    float htA = yoA * tcA;
    float htB = yoB * tcB;

    if (g == 0) {
      _Float16 hA = (_Float16)htA;
      _Float16 hB = (_Float16)htB;
      hb[0][cur ^ 1][k] = hA;
      hb[1][cur ^ 1][k] = hB;
      hist[0][t & 15][k] = hA;
      hist[1][t & 15][k] = hB;
    }

    if ((s & 15) == 15) {
      // 16 hist rows complete for both seqs -> bulk flush (16B stores)
      __syncthreads();
      const int base = t & ~15;
      const int seq = tid >> 8;          // 0 or 1
      const int rem = tid & 255;
      const int tl = rem >> 4, q = rem & 15;
      h8_t v8 = *(const h8_t*)(&hist[seq][tl][q << 3]);
      *(h8_t*)(hs + (((size_t)((b0 + seq) << 9) + base + tl) << 8) +
               (dir << 7) + (q << 3)) = v8;
    }
    __syncthreads();
    pvA = pvnA;
    pvB = pvnB;
    cur ^= 1;
  }
}

// ---------------------------------------------------------------------------
// K3: out[row, v] = dot(hs[row, 0:256], fc_w[v, 0:256]) + fc_b[v]
// ---------------------------------------------------------------------------
__global__ __launch_bounds__(256) void k_fc(
    const _Float16* __restrict__ hs,
    const float* __restrict__ fc_w,
    const float* __restrict__ fc_b,
    float* __restrict__ out) {
  __shared__ __align__(16) _Float16 Wl[V_ * 2 * H_];  // 32 KB
  __shared__ float bl[V_];
  const int tid = threadIdx.x;
  for (int i = tid; i < V_ * 2 * H_; i += 256) Wl[i] = (_Float16)fc_w[i];
  if (tid < V_) bl[tid] = fc_b[tid];
  __syncthreads();

  const size_t row = (size_t)blockIdx.x * 256 + tid;
  const h8_t* h8 = (const h8_t*)(hs + (row << 8));
  float acc[V_];
#pragma unroll
  for (int v = 0; v < V_; ++v) acc[v] = 0.f;

  for (int ch = 0; ch < 8; ++ch) {  // 8 chunks of 32 h-elements
    h8s hv0 = __builtin_bit_cast(h8s, h8[ch * 4 + 0]);
    h8s hv1 = __builtin_bit_cast(h8s, h8[ch * 4 + 1]);
    h8s hv2 = __builtin_bit_cast(h8s, h8[ch * 4 + 2]);
    h8s hv3 = __builtin_bit_cast(h8s, h8[ch * 4 + 3]);
#pragma unroll
    for (int v = 0; v < V_; ++v) {
      const h8_t* w8 = (const h8_t*)(Wl + v * 256 + ch * 32);
      float a = acc[v];
      h8s wv = __builtin_bit_cast(h8s, w8[0]);
      a = dot2f(hv0.p[0], wv.p[0], a);
      a = dot2f(hv0.p[1], wv.p[1], a);
      a = dot2f(hv0.p[2], wv.p[2], a);
      a = dot2f(hv0.p[3], wv.p[3], a);
      wv = __builtin_bit_cast(h8s, w8[1]);
      a = dot2f(hv1.p[0], wv.p[0], a);
      a = dot2f(hv1.p[1], wv.p[1], a);
      a = dot2f(hv1.p[2], wv.p[2], a);
      a = dot2f(hv1.p[3], wv.p[3], a);
      wv = __builtin_bit_cast(h8s, w8[2]);
      a = dot2f(hv2.p[0], wv.p[0], a);
      a = dot2f(hv2.p[1], wv.p[1], a);
      a = dot2f(hv2.p[2], wv.p[2], a);
      a = dot2f(hv2.p[3], wv.p[3], a);
      wv = __builtin_bit_cast(h8s, w8[3]);
      a = dot2f(hv3.p[0], wv.p[0], a);
      a = dot2f(hv3.p[1], wv.p[1], a);
      a = dot2f(hv3.p[2], wv.p[2], a);
      a = dot2f(hv3.p[3], wv.p[3], a);
      acc[v] = a;
    }
  }
  float* orow = out + (row << 6);
#pragma unroll
  for (int v = 0; v < V_; v += 4) {
    float4 o = make_float4(acc[v] + bl[v], acc[v + 1] + bl[v + 1],
                           acc[v + 2] + bl[v + 2], acc[v + 3] + bl[v + 3]);
    *(float4*)(orow + v) = o;
  }
}

extern "C" void kernel_launch(void* const* d_in, const int* in_sizes, int n_in,
                              void* d_out, int out_size, void* d_ws, size_t ws_size,
                              hipStream_t stream) {
  const int* x = (const int*)d_in[0];
  const float* emb = (const float*)d_in[1];
  const float* w_ih_f = (const float*)d_in[2];
  const float* w_hh_f = (const float*)d_in[3];
  const float* b_ih_f = (const float*)d_in[4];
  const float* b_hh_f = (const float*)d_in[5];
  const float* w_ih_b = (const float*)d_in[6];
  const float* w_hh_b = (const float*)d_in[7];
  const float* b_ih_b = (const float*)d_in[8];
  const float* b_hh_b = (const float*)d_in[9];
  const float* fc_w = (const float*)d_in[10];
  const float* fc_b = (const float*)d_in[11];
  float* out = (float*)d_out;

  // workspace layout: [P tables: 2*64*512 fp32 = 256 KB][hs: B*T*256 fp16 = 32 MB]
  float* Ptab = (float*)d_ws;
  _Float16* hs = (_Float16*)((char*)d_ws + (size_t)2 * V_ * G4_ * sizeof(float));

  k_tables<<<2 * V_, G4_, 0, stream>>>(emb, w_ih_f, b_ih_f, b_hh_f, w_ih_b,
                                       b_ih_b, b_hh_b, Ptab);
  k_scan<<<B_, 512, 0, stream>>>(x, w_hh_f, w_hh_b, Ptab, hs);
  k_fc<<<B_ * T_ / 256, 256, 0, stream>>>(hs, fc_w, fc_b, out);
}

// Round 7
// 372.932 us; speedup vs baseline: 1.4642x; 1.4642x over previous
//
#include <hip/hip_runtime.h>
#include <hip/hip_bf16.h>

#define B_ 128
#define T_ 512
#define H_ 128
#define V_ 64
#define G4_ 512  // 4*H

typedef _Float16 h2_t __attribute__((ext_vector_type(2)));
typedef _Float16 h8_t __attribute__((ext_vector_type(8)));
struct h8s { h2_t p[4]; };

__device__ __forceinline__ float dot2f(h2_t a, h2_t b, float c) {
#if __has_builtin(__builtin_amdgcn_fdot2)
  return __builtin_amdgcn_fdot2(a, b, c, false);
#else
  return fmaf((float)a[1], (float)b[1], fmaf((float)a[0], (float)b[0], c));
#endif
}

__device__ __forceinline__ float ex2(float x) {
#if __has_builtin(__builtin_amdgcn_exp2f)
  return __builtin_amdgcn_exp2f(x);
#else
  return exp2f(x);
#endif
}

__device__ __forceinline__ float rcpf_(float x) {
#if __has_builtin(__builtin_amdgcn_rcpf)
  return __builtin_amdgcn_rcpf(x);
#else
  return 1.0f / x;
#endif
}

// DPP quad-perm controls
#define QP_XOR1 0xB1  // [1,0,3,2]
#define QP_XOR2 0x4E  // [2,3,0,1]
#define QP_BC0 0x00
#define QP_BC1 0x55
#define QP_BC2 0xAA
#define QP_BC3 0xFF

template <int CTRL>
__device__ __forceinline__ float qperm(float v) {
#if __has_builtin(__builtin_amdgcn_update_dpp)
  return __builtin_bit_cast(
      float, __builtin_amdgcn_update_dpp(0, __builtin_bit_cast(int, v), CTRL,
                                         0xf, 0xf, true));
#else
  int lane = (int)(threadIdx.x & 3);
  int src;
  if constexpr (CTRL == QP_XOR1) src = lane ^ 1;
  else if constexpr (CTRL == QP_XOR2) src = lane ^ 2;
  else src = CTRL & 3;
  return __shfl(v, ((int)threadIdx.x & ~3) + src, 64);
#endif
}

// ---------------------------------------------------------------------------
// K1: P table in layout [dir][v][Q][g][j]  (Q=k&63, j=k>>6, row=g*128+k)
// so k_scan lane (Q,q) loads its 2 P values as one float2.
// ---------------------------------------------------------------------------
__global__ __launch_bounds__(512) void k_tables(
    const float* __restrict__ emb,
    const float* __restrict__ w_ih_f, const float* __restrict__ b_ih_f,
    const float* __restrict__ b_hh_f,
    const float* __restrict__ w_ih_b, const float* __restrict__ b_ih_b,
    const float* __restrict__ b_hh_b,
    float* __restrict__ Ptab) {
  const int dir = blockIdx.x >> 6;
  const int v = blockIdx.x & 63;
  const int j0 = threadIdx.x;  // row = g*128 + k
  const float* w_ih = dir ? w_ih_b : w_ih_f;
  const float* bi = dir ? b_ih_b : b_ih_f;
  const float* bh = dir ? b_hh_b : b_hh_f;
  const float4* e4 = (const float4*)(emb + v * H_);
  const float4* w4 = (const float4*)(w_ih + j0 * H_);
  float a0 = 0.f, a1 = 0.f, a2 = 0.f, a3 = 0.f;
#pragma unroll
  for (int q = 0; q < H_ / 4; ++q) {
    float4 e = e4[q];
    float4 w = w4[q];
    a0 = fmaf(e.x, w.x, a0);
    a1 = fmaf(e.y, w.y, a1);
    a2 = fmaf(e.z, w.z, a2);
    a3 = fmaf(e.w, w.w, a3);
  }
  const int g = j0 >> 7, k = j0 & 127;
  const int Q = k & 63, jj = k >> 6;
  Ptab[dir * (V_ * G4_) + v * G4_ + (Q << 3) + (g << 1) + jj] =
      (a0 + a1) + (a2 + a3) + bi[j0] + bh[j0];
}

// ---------------------------------------------------------------------------
// K2: per-(batch,dir) scan, 256 threads (4 waves). grid = 256.
// Lane l: Q = l>>2 (global quad id 0..63), q = l&3 (gate AND k-quarter).
// Lane computes 8 rows {gate g, k in {Q, Q+64}} over h-quarter [q*32,+32):
// 128 dot2, weights 128 VGPR. Quad transpose-reduce -> lane q holds rows
// (gate q, k=Q) and (gate q, k=Q+64). P from GLOBAL (L2-resident, float2,
// prefetched 1 step ahead) - no 128KB LDS table, 4-wave barrier, half the
// DS-port drain of the 512-thread version.
// ---------------------------------------------------------------------------
__global__ __launch_bounds__(256, 1) void k_scan(
    const int* __restrict__ x,
    const float* __restrict__ w_hh_f,
    const float* __restrict__ w_hh_b,
    const float* __restrict__ Ptab,
    _Float16* __restrict__ hs) {
  __shared__ int xoff[T_];                             // 2 KB (v<<9)
  __shared__ __align__(16) _Float16 hb[2][H_];         // 512 B
  __shared__ __align__(16) _Float16 hist[16][H_];      // 4 KB

  const int tid = threadIdx.x;
  const int b = blockIdx.x >> 1;
  const int dir = blockIdx.x & 1;
  const int Q = tid >> 2;   // 0..63
  const int q = tid & 3;    // gate / k-quarter

  xoff[tid] = x[(b << 9) + tid] << 9;
  xoff[256 + tid] = x[(b << 9) + 256 + tid] << 9;
  if (tid < H_) hb[0][tid] = (_Float16)0.f;

  // weights: 8 rows (g in 0..3, jj in 0..1 -> row g*128 + Q + 64*jj),
  // elements [q*32, q*32+32), fp16 pairs. 128 VGPRs.
  const float* W = dir ? w_hh_b : w_hh_f;
  h2_t wr[4][2][16];
#pragma unroll
  for (int g = 0; g < 4; ++g)
#pragma unroll
    for (int jj = 0; jj < 2; ++jj) {
      const float2* wp =
          (const float2*)(W + (g * H_ + Q + 64 * jj) * H_ + q * 32);
#pragma unroll
      for (int e = 0; e < 16; ++e) {
        float2 ww = wp[e];
        wr[g][jj][e] = h2_t{(_Float16)ww.x, (_Float16)ww.y};
      }
    }

  // per-lane nonlinearity constants: sigm for q in {0,1,3}, tanh for q==2
  const float nm = (q == 2) ? -2.8853900817779268f : -1.4426950408889634f;
  const float sa = (q == 2) ? 2.f : 1.f;
  const float sb = (q == 2) ? -1.f : 0.f;

  float c0 = 0.f, c1 = 0.f;  // c[Q], c[Q+64] (replicated in quad)

  const float* Pg = Ptab + dir * (V_ * G4_) + (Q << 3) + (q << 1);

  __syncthreads();

  // preload step-0 P pair
  const int t0 = dir ? (T_ - 1) : 0;
  float2 pv = *(const float2*)(Pg + xoff[t0]);

  int cur = 0;
  for (int s = 0; s < T_; ++s) {
    const int t = dir ? (T_ - 1 - s) : s;
    // h quarter q: 4x ds_read_b128 (16-lane same-address broadcast)
    const h8_t* hq8 = (const h8_t*)(&hb[cur][q << 5]);
    h8s h0 = __builtin_bit_cast(h8s, hq8[0]);
    h8s h1 = __builtin_bit_cast(h8s, hq8[1]);
    h8s h2v = __builtin_bit_cast(h8s, hq8[2]);
    h8s h3 = __builtin_bit_cast(h8s, hq8[3]);

    // prefetch next step's P pair from L2 (used next iteration)
    const int sn = (s < T_ - 1) ? s + 1 : s;
    const int tn = dir ? (T_ - 1 - sn) : sn;
    const float2 pvn = *(const float2*)(Pg + xoff[tn]);

    float a00 = 0.f, a01 = 0.f, a10 = 0.f, a11 = 0.f;
    float a20 = 0.f, a21 = 0.f, a30 = 0.f, a31 = 0.f;
#pragma unroll
    for (int e = 0; e < 4; ++e) {
      a00 = dot2f(h0.p[e], wr[0][0][e], a00);
      a01 = dot2f(h0.p[e], wr[0][1][e], a01);
      a10 = dot2f(h0.p[e], wr[1][0][e], a10);
      a11 = dot2f(h0.p[e], wr[1][1][e], a11);
      a20 = dot2f(h0.p[e], wr[2][0][e], a20);
      a21 = dot2f(h0.p[e], wr[2][1][e], a21);
      a30 = dot2f(h0.p[e], wr[3][0][e], a30);
      a31 = dot2f(h0.p[e], wr[3][1][e], a31);
    }
#pragma unroll
    for (int e = 0; e < 4; ++e) {
      a00 = dot2f(h1.p[e], wr[0][0][4 + e], a00);
      a01 = dot2f(h1.p[e], wr[0][1][4 + e], a01);
      a10 = dot2f(h1.p[e], wr[1][0][4 + e], a10);
      a11 = dot2f(h1.p[e], wr[1][1][4 + e], a11);
      a20 = dot2f(h1.p[e], wr[2][0][4 + e], a20);
      a21 = dot2f(h1.p[e], wr[2][1][4 + e], a21);
      a30 = dot2f(h1.p[e], wr[3][0][4 + e], a30);
      a31 = dot2f(h1.p[e], wr[3][1][4 + e], a31);
    }
#pragma unroll
    for (int e = 0; e < 4; ++e) {
      a00 = dot2f(h2v.p[e], wr[0][0][8 + e], a00);
      a01 = dot2f(h2v.p[e], wr[0][1][8 + e], a01);
      a10 = dot2f(h2v.p[e], wr[1][0][8 + e], a10);
      a11 = dot2f(h2v.p[e], wr[1][1][8 + e], a11);
      a20 = dot2f(h2v.p[e], wr[2][0][8 + e], a20);
      a21 = dot2f(h2v.p[e], wr[2][1][8 + e], a21);
      a30 = dot2f(h2v.p[e], wr[3][0][8 + e], a30);
      a31 = dot2f(h2v.p[e], wr[3][1][8 + e], a31);
    }
#pragma unroll
    for (int e = 0; e < 4; ++e) {
      a00 = dot2f(h3.p[e], wr[0][0][12 + e], a00);
      a01 = dot2f(h3.p[e], wr[0][1][12 + e], a01);
      a10 = dot2f(h3.p[e], wr[1][0][12 + e], a10);
      a11 = dot2f(h3.p[e], wr[1][1][12 + e], a11);
      a20 = dot2f(h3.p[e], wr[2][0][12 + e], a20);
      a21 = dot2f(h3.p[e], wr[2][1][12 + e], a21);
      a30 = dot2f(h3.p[e], wr[3][0][12 + e], a30);
      a31 = dot2f(h3.p[e], wr[3][1][12 + e], a31);
    }

    // quad transpose-reduce, jj=0 and jj=1 independently:
    // lane q ends with full row (gate q, k=Q) and (gate q, k=Q+64)
    float s00 = a00 + qperm<QP_XOR1>(a00);
    float s10 = a10 + qperm<QP_XOR1>(a10);
    float s20 = a20 + qperm<QP_XOR1>(a20);
    float s30 = a30 + qperm<QP_XOR1>(a30);
    float s01 = a01 + qperm<QP_XOR1>(a01);
    float s11 = a11 + qperm<QP_XOR1>(a11);
    float s21 = a21 + qperm<QP_XOR1>(a21);
    float s31 = a31 + qperm<QP_XOR1>(a31);
    float mA0 = (q & 1) ? s10 : s00;
    float mB0 = (q & 1) ? s30 : s20;
    float mA1 = (q & 1) ? s11 : s01;
    float mB1 = (q & 1) ? s31 : s21;
    float uA0 = mA0 + qperm<QP_XOR2>(mA0);
    float uB0 = mB0 + qperm<QP_XOR2>(mB0);
    float uA1 = mA1 + qperm<QP_XOR2>(mA1);
    float uB1 = mB1 + qperm<QP_XOR2>(mB1);
    float gv0 = ((q & 2) ? uB0 : uA0) + pv.x;
    float gv1 = ((q & 2) ? uB1 : uA1) + pv.y;

    // nonlinearity (uniform code, per-lane constants)
    float y0 = fmaf(sa, rcpf_(1.f + ex2(nm * gv0)), sb);
    float y1 = fmaf(sa, rcpf_(1.f + ex2(nm * gv1)), sb);

    // quad broadcast: gates of k0 from slot0, k1 from slot1
    float yi0 = qperm<QP_BC0>(y0);
    float yf0 = qperm<QP_BC1>(y0);
    float yg0 = qperm<QP_BC2>(y0);
    float yo0 = qperm<QP_BC3>(y0);
    float yi1 = qperm<QP_BC0>(y1);
    float yf1 = qperm<QP_BC1>(y1);
    float yg1 = qperm<QP_BC2>(y1);
    float yo1 = qperm<QP_BC3>(y1);

    c0 = fmaf(yf0, c0, yi0 * yg0);
    c1 = fmaf(yf1, c1, yi1 * yg1);
    float tc0 = fmaf(2.f, rcpf_(1.f + ex2(-2.8853900817779268f * c0)), -1.f);
    float tc1 = fmaf(2.f, rcpf_(1.f + ex2(-2.8853900817779268f * c1)), -1.f);
    float ht0 = yo0 * tc0;
    float ht1 = yo1 * tc1;

    if (q == 0) {
      _Float16 h0w = (_Float16)ht0;
      _Float16 h1w = (_Float16)ht1;
      hb[cur ^ 1][Q] = h0w;
      hb[cur ^ 1][Q + 64] = h1w;
      hist[t & 15][Q] = h0w;
      hist[t & 15][Q + 64] = h1w;
    }
    __syncthreads();

    if ((s & 15) == 15) {
      // 16 hist rows complete -> bulk flush (coalesced 16B stores)
      const int base = t & ~15;
      const int tl = tid >> 4, ch = tid & 15;
      h8_t v8 = *(const h8_t*)(&hist[tl][ch << 3]);
      *(h8_t*)(hs + (((size_t)((b << 9) + base + tl)) << 8) + (dir << 7) +
               (ch << 3)) = v8;
    }
    pv = pvn;
    cur ^= 1;
  }
}

// ---------------------------------------------------------------------------
// K3: out[row, v] = dot(hs[row, 0:256], fc_w[v, 0:256]) + fc_b[v]
// ---------------------------------------------------------------------------
__global__ __launch_bounds__(256) void k_fc(
    const _Float16* __restrict__ hs,
    const float* __restrict__ fc_w,
    const float* __restrict__ fc_b,
    float* __restrict__ out) {
  __shared__ __align__(16) _Float16 Wl[V_ * 2 * H_];  // 32 KB
  __shared__ float bl[V_];
  const int tid = threadIdx.x;
  for (int i = tid; i < V_ * 2 * H_; i += 256) Wl[i] = (_Float16)fc_w[i];
  if (tid < V_) bl[tid] = fc_b[tid];
  __syncthreads();

  const size_t row = (size_t)blockIdx.x * 256 + tid;
  const h8_t* h8 = (const h8_t*)(hs + (row << 8));
  float acc[V_];
#pragma unroll
  for (int v = 0; v < V_; ++v) acc[v] = 0.f;

  for (int ch = 0; ch < 8; ++ch) {  // 8 chunks of 32 h-elements
    h8s hv0 = __builtin_bit_cast(h8s, h8[ch * 4 + 0]);
    h8s hv1 = __builtin_bit_cast(h8s, h8[ch * 4 + 1]);
    h8s hv2 = __builtin_bit_cast(h8s, h8[ch * 4 + 2]);
    h8s hv3 = __builtin_bit_cast(h8s, h8[ch * 4 + 3]);
#pragma unroll
    for (int v = 0; v < V_; ++v) {
      const h8_t* w8 = (const h8_t*)(Wl + v * 256 + ch * 32);
      float a = acc[v];
      h8s wv = __builtin_bit_cast(h8s, w8[0]);
      a = dot2f(hv0.p[0], wv.p[0], a);
      a = dot2f(hv0.p[1], wv.p[1], a);
      a = dot2f(hv0.p[2], wv.p[2], a);
      a = dot2f(hv0.p[3], wv.p[3], a);
      wv = __builtin_bit_cast(h8s, w8[1]);
      a = dot2f(hv1.p[0], wv.p[0], a);
      a = dot2f(hv1.p[1], wv.p[1], a);
      a = dot2f(hv1.p[2], wv.p[2], a);
      a = dot2f(hv1.p[3], wv.p[3], a);
      wv = __builtin_bit_cast(h8s, w8[2]);
      a = dot2f(hv2.p[0], wv.p[0], a);
      a = dot2f(hv2.p[1], wv.p[1], a);
      a = dot2f(hv2.p[2], wv.p[2], a);
      a = dot2f(hv2.p[3], wv.p[3], a);
      wv = __builtin_bit_cast(h8s, w8[3]);
      a = dot2f(hv3.p[0], wv.p[0], a);
      a = dot2f(hv3.p[1], wv.p[1], a);
      a = dot2f(hv3.p[2], wv.p[2], a);
      a = dot2f(hv3.p[3], wv.p[3], a);
      acc[v] = a;
    }
  }
  float* orow = out + (row << 6);
#pragma unroll
  for (int v = 0; v < V_; v += 4) {
    float4 o = make_float4(acc[v] + bl[v], acc[v + 1] + bl[v + 1],
                           acc[v + 2] + bl[v + 2], acc[v + 3] + bl[v + 3]);
    *(float4*)(orow + v) = o;
  }
}

extern "C" void kernel_launch(void* const* d_in, const int* in_sizes, int n_in,
                              void* d_out, int out_size, void* d_ws, size_t ws_size,
                              hipStream_t stream) {
  const int* x = (const int*)d_in[0];
  const float* emb = (const float*)d_in[1];
  const float* w_ih_f = (const float*)d_in[2];
  const float* w_hh_f = (const float*)d_in[3];
  const float* b_ih_f = (const float*)d_in[4];
  const float* b_hh_f = (const float*)d_in[5];
  const float* w_ih_b = (const float*)d_in[6];
  const float* w_hh_b = (const float*)d_in[7];
  const float* b_ih_b = (const float*)d_in[8];
  const float* b_hh_b = (const float*)d_in[9];
  const float* fc_w = (const float*)d_in[10];
  const float* fc_b = (const float*)d_in[11];
  float* out = (float*)d_out;

  // workspace layout: [P tables: 2*64*512 fp32 = 256 KB][hs: B*T*256 fp16 = 32 MB]
  float* Ptab = (float*)d_ws;
  _Float16* hs = (_Float16*)((char*)d_ws + (size_t)2 * V_ * G4_ * sizeof(float));

  k_tables<<<2 * V_, G4_, 0, stream>>>(emb, w_ih_f, b_ih_f, b_hh_f, w_ih_b,
                                       b_ih_b, b_hh_b, Ptab);
  k_scan<<<B_ * 2, 256, 0, stream>>>(x, w_hh_f, w_hh_b, Ptab, hs);
  k_fc<<<B_ * T_ / 256, 256, 0, stream>>>(hs, fc_w, fc_b, out);
}